// Round 6
// baseline (231.434 us; speedup 1.0000x reference)
//
#include <hip/hip_runtime.h>
#include <math.h>

// Problem dims (fixed by reference)
#define SE_B 64
#define SE_C 256
#define SE_L 4096
#define SE_R 16

#define NBLK 2048   // 8 blocks/CU x 256 CU = exact co-residency (proven R4)
#define ROUNDS 8    // 16384 rows / 2048 blocks
#define BIAS 4.0f   // published values are val+BIAS so sentinel 0.0f is unambiguous

typedef float vf4 __attribute__((ext_vector_type(4)));

// ---------------------------------------------------------------------------
// Persistent fused SE kernel, FENCE-FREE sync (data-as-token):
//  - each block owns one (b,c) row per round; the row lives in 16 VGPRs
//    between the mean phase and the scale phase -> x is read from HBM ONCE.
//  - sync uses ONLY relaxed agent-scope atomics (no release/acquire): on
//    gfx950 acquire/release at agent scope flash-invalidate/write-back the
//    per-XCD L2 (R4: 2.2 ms meltdown). Relaxed ops have no cache side
//    effects; the polled VALUE itself is the token (biased by +4 so the
//    0.0f sentinel from the launch-start memset is unambiguous).
//  - bid&7 == XCD under round-robin dispatch: batch b's 256 blocks all land
//    on one XCD (32 CU x 8 blocks) -> per-batch sync stays local-ish and
//    each XCD streams a contiguous 32 MB batch per round.
//  - scale blocks prefetch the next round's row BEFORE polling their gate,
//    so sync latency hides under VMEM latency.
// ---------------------------------------------------------------------------
__global__ __launch_bounds__(256, 8) void se_fused_kernel(
    const float* __restrict__ x, const float* __restrict__ w1,
    const float* __restrict__ b1, const float* __restrict__ w2,
    const float* __restrict__ b2, float* __restrict__ out,
    float* means, float* gates) {
  const int t = threadIdx.x;
  const int r = blockIdx.x & 7;       // sub-round lane (== XCD id, likely)
  const int s = blockIdx.x >> 3;      // channel 0..255
  const bool is_gate = (s == 0);      // channel-0 block computes the batch gate

  __shared__ float m_lds[SE_C];
  __shared__ float yp[SE_R][SE_R + 1];
  __shared__ float y_lds[SE_R];
  __shared__ float red[4];
  __shared__ float bcast;

  // prologue: load round-0 row into registers
  size_t row = (size_t)r * SE_C + s;
  {
    const vf4* __restrict__ xr = reinterpret_cast<const vf4*>(x + row * SE_L);
    // fallthrough into loop body uses d0..d3
  }
  const vf4* __restrict__ xr0 = reinterpret_cast<const vf4*>(x + row * SE_L);
  vf4 d0 = xr0[t], d1 = xr0[t + 256], d2 = xr0[t + 512], d3 = xr0[t + 768];

  for (int round = 0; round < ROUNDS; ++round) {
    const int b = round * 8 + r;
    row = (size_t)b * SE_C + s;

    // ---- mean of the register-resident row ----
    float sum = ((d0.x + d0.y) + (d0.z + d0.w)) + ((d1.x + d1.y) + (d1.z + d1.w)) +
                ((d2.x + d2.y) + (d2.z + d2.w)) + ((d3.x + d3.y) + (d3.z + d3.w));
#pragma unroll
    for (int off = 32; off > 0; off >>= 1) sum += __shfl_down(sum, off, 64);
    if ((t & 63) == 0) red[t >> 6] = sum;
    __syncthreads();
    if (t == 0) {
      float mean = ((red[0] + red[1]) + (red[2] + red[3])) * (1.0f / SE_L);
      __hip_atomic_store(&means[row], mean + BIAS, __ATOMIC_RELAXED,
                         __HIP_MEMORY_SCOPE_AGENT);
    }

    const bool havenext = (round + 1 < ROUNDS);
    vf4 e0, e1, e2, e3;

    float g;
    if (!is_gate) {
      // prefetch next round's row BEFORE polling: hides sync under VMEM
      if (havenext) {
        const vf4* __restrict__ xn =
            reinterpret_cast<const vf4*>(x + (row + 8 * SE_C) * SE_L);
        e0 = xn[t]; e1 = xn[t + 256]; e2 = xn[t + 512]; e3 = xn[t + 768];
      }
      if (t == 0) {
        float gv;
        int guard = 0;
        while ((gv = __hip_atomic_load(&gates[row], __ATOMIC_RELAXED,
                                       __HIP_MEMORY_SCOPE_AGENT)) == 0.0f) {
          __builtin_amdgcn_s_sleep(16);
          if (++guard > (1 << 18)) break;  // loud failure (g=-4), never a hang
        }
        bcast = gv - BIAS;
      }
      __syncthreads();
      g = bcast;
    } else {
      // ---- gate block: poll all 256 means of batch b (value == token) ----
      {
        float mv;
        int guard = 0;
        const float* mp = &means[(size_t)b * SE_C + t];
        while ((mv = __hip_atomic_load(mp, __ATOMIC_RELAXED,
                                       __HIP_MEMORY_SCOPE_AGENT)) == 0.0f) {
          __builtin_amdgcn_s_sleep(16);
          if (++guard > (1 << 18)) break;
        }
        m_lds[t] = mv - BIAS;
      }
      __syncthreads();
      // hidden layer: group gq (16 thr) computes y[gq]
      const int gq = t >> 4, j = t & 15;
      float part = 0.0f;
      const float* __restrict__ w1g = w1 + (gq << 8);
#pragma unroll
      for (int k = 0; k < 16; ++k) {
        const int ch = j + (k << 4);
        part += m_lds[ch] * w1g[ch];
      }
      yp[gq][j] = part;
      __syncthreads();
      if (t < SE_R) {
        float acc = b1[t];
#pragma unroll
        for (int k = 0; k < 16; ++k) acc += yp[t][k];
        y_lds[t] = fmaxf(acc, 0.0f);
      }
      __syncthreads();
      // thread t computes the gate for channel t, publishes it
      float gg = b2[t];
      const float* __restrict__ w2c = w2 + (t << 4);
#pragma unroll
      for (int k = 0; k < SE_R; ++k) gg += y_lds[k] * w2c[k];
      gg = 1.0f / (1.0f + expf(-gg));
      __hip_atomic_store(&gates[(size_t)b * SE_C + t], gg + BIAS,
                         __ATOMIC_RELAXED, __HIP_MEMORY_SCOPE_AGENT);
      if (t == 0) bcast = gg;  // own row is channel 0
      __syncthreads();
      g = bcast;
      // prefetch after MLP (keeps e-regs from overlapping MLP temps)
      if (havenext) {
        const vf4* __restrict__ xn =
            reinterpret_cast<const vf4*>(x + (row + 8 * SE_C) * SE_L);
        e0 = xn[t]; e1 = xn[t + 256]; e2 = xn[t + 512]; e3 = xn[t + 768];
      }
    }

    // ---- scale the register-resident row, streaming store ----
    vf4* __restrict__ orow = reinterpret_cast<vf4*>(out + row * SE_L);
    __builtin_nontemporal_store(d0 * g, &orow[t]);
    __builtin_nontemporal_store(d1 * g, &orow[t + 256]);
    __builtin_nontemporal_store(d2 * g, &orow[t + 512]);
    __builtin_nontemporal_store(d3 * g, &orow[t + 768]);

    if (havenext) { d0 = e0; d1 = e1; d2 = e2; d3 = e3; }
    __syncthreads();  // LDS (red/m_lds/bcast) reuse next round
  }
}

extern "C" void kernel_launch(void* const* d_in, const int* in_sizes, int n_in,
                              void* d_out, int out_size, void* d_ws,
                              size_t ws_size, hipStream_t stream) {
  const float* x = (const float*)d_in[0];
  const float* w1 = (const float*)d_in[1];
  const float* b1 = (const float*)d_in[2];
  const float* w2 = (const float*)d_in[3];
  const float* b2 = (const float*)d_in[4];
  float* out = (float*)d_out;

  float* means = (float*)d_ws;                  // 16384 floats
  float* gates = means + SE_B * SE_C;           // 16384 floats

  // reset sentinels every replay (captured in graph, ordered on stream)
  hipMemsetAsync(d_ws, 0, 2 * SE_B * SE_C * sizeof(float), stream);

  se_fused_kernel<<<NBLK, 256, 0, stream>>>(x, w1, b1, w2, b2, out, means,
                                            gates);
}

// Round 7
// 132.726 us; speedup vs baseline: 1.7437x; 1.7437x over previous
//
#include <hip/hip_runtime.h>
#include <math.h>

// Problem dims (fixed by reference)
#define SE_B 64
#define SE_C 256
#define SE_L 4096
#define SE_R 16

// Clang native vector type (required by __builtin_nontemporal_store).
typedef float vf4 __attribute__((ext_vector_type(4)));

// ---------------------------------------------------------------------------
// Kernel 1: per-(b,c) mean over L. One block per row, 256 threads.
// Reads x FORWARD (ascending addresses), allocating x into the MALL.
// ---------------------------------------------------------------------------
__global__ __launch_bounds__(256) void se_mean_kernel(
    const float* __restrict__ x, float* __restrict__ means) {
  const int row = blockIdx.x;  // b*C + c
  const int t = threadIdx.x;
  const vf4* __restrict__ xrow =
      reinterpret_cast<const vf4*>(x + (size_t)row * SE_L);
  float s = 0.0f;
#pragma unroll
  for (int i = 0; i < 4; ++i) {
    vf4 v = xrow[t + i * 256];  // coalesced
    s += (v.x + v.y) + (v.z + v.w);
  }
#pragma unroll
  for (int off = 32; off > 0; off >>= 1) s += __shfl_down(s, off, 64);
  __shared__ float partial[4];
  if ((t & 63) == 0) partial[t >> 6] = s;
  __syncthreads();
  if (t == 0) {
    float tot = (partial[0] + partial[1]) + (partial[2] + partial[3]);
    means[row] = tot * (1.0f / SE_L);
  }
}

// ---------------------------------------------------------------------------
// Kernel 2: tiny 2-layer MLP gate per batch. One block per b, 256 threads.
// ---------------------------------------------------------------------------
__global__ __launch_bounds__(256) void se_gate_kernel(
    const float* __restrict__ means, const float* __restrict__ w1,
    const float* __restrict__ b1, const float* __restrict__ w2,
    const float* __restrict__ b2, float* __restrict__ gates) {
  const int b = blockIdx.x;
  const int t = threadIdx.x;
  __shared__ float m[SE_C];
  __shared__ float y[SE_R];
  m[t] = means[b * SE_C + t];
  __syncthreads();
  if (t < SE_R) {
    float acc = b1[t];
    const float* __restrict__ w1r = w1 + t * SE_C;
#pragma unroll 8
    for (int c = 0; c < SE_C; ++c) acc += m[c] * w1r[c];
    y[t] = fmaxf(acc, 0.0f);
  }
  __syncthreads();
  float g = b2[t];
  const float* __restrict__ w2r = w2 + t * SE_R;
#pragma unroll
  for (int r = 0; r < SE_R; ++r) g += y[r] * w2r[r];
  gates[b * SE_C + t] = 1.0f / (1.0f + expf(-g));
}

// ---------------------------------------------------------------------------
// Kernel 3: out[b,c,l] = x[b,c,l] * gate[b,c]. Grid-stride vf4, traversed in
// REVERSE address order. x == MALL size (256 MB): same-order re-read is the
// LRU worst case (every line evicted just before we reach it); reverse order
// reads the freshest (tail) lines first -> x line at distance p from the tail
// has age ~2p (K1 tail + out writes), so the back ~half of the re-read hits
// the Infinity Cache. Lanes within a wave still cover one contiguous 4 KB
// span (full coalescing); only the sweep direction changes.
// Stores remain non-temporal.
// ---------------------------------------------------------------------------
__global__ __launch_bounds__(256) void se_scale_kernel(
    const float* __restrict__ x, const float* __restrict__ gates,
    float* __restrict__ out) {
  const size_t n4 = (size_t)SE_B * SE_C * (SE_L / 4);  // 16,777,216
  const size_t stride = (size_t)gridDim.x * blockDim.x;
  const vf4* __restrict__ x4 = reinterpret_cast<const vf4*>(x);
  vf4* __restrict__ o4 = reinterpret_cast<vf4*>(out);
  for (size_t i = (size_t)blockIdx.x * blockDim.x + threadIdx.x; i < n4;
       i += stride) {
    const size_t j = n4 - 1 - i;  // descending sweep
    const int row = (int)(j >> 10);
    const float g = gates[row];
    vf4 v = x4[j];
    v *= g;
    __builtin_nontemporal_store(v, &o4[j]);
  }
}

extern "C" void kernel_launch(void* const* d_in, const int* in_sizes, int n_in,
                              void* d_out, int out_size, void* d_ws,
                              size_t ws_size, hipStream_t stream) {
  const float* x = (const float*)d_in[0];
  const float* w1 = (const float*)d_in[1];
  const float* b1 = (const float*)d_in[2];
  const float* w2 = (const float*)d_in[3];
  const float* b2 = (const float*)d_in[4];
  float* out = (float*)d_out;

  float* means = (float*)d_ws;             // B*C floats
  float* gates = means + SE_B * SE_C;      // B*C floats

  se_mean_kernel<<<SE_B * SE_C, 256, 0, stream>>>(x, means);
  se_gate_kernel<<<SE_B, SE_C, 0, stream>>>(means, w1, b1, w2, b2, gates);
  se_scale_kernel<<<2048, 256, 0, stream>>>(x, gates, out);
}

// Round 8
// 122.329 us; speedup vs baseline: 1.8919x; 1.0850x over previous
//
#include <hip/hip_runtime.h>
#include <math.h>

// Problem dims (fixed by reference)
#define SE_B 64
#define SE_C 256
#define SE_L 4096
#define SE_R 16

// Clang native vector type (required by __builtin_nontemporal_store).
typedef float vf4 __attribute__((ext_vector_type(4)));

// ---------------------------------------------------------------------------
// Kernel 1: per-(b,c) mean over L. One block per row, 256 threads.
// ---------------------------------------------------------------------------
__global__ __launch_bounds__(256) void se_mean_kernel(
    const float* __restrict__ x, float* __restrict__ means) {
  const int row = blockIdx.x;  // b*C + c
  const int t = threadIdx.x;
  const vf4* __restrict__ xrow =
      reinterpret_cast<const vf4*>(x + (size_t)row * SE_L);
  float s = 0.0f;
#pragma unroll
  for (int i = 0; i < 4; ++i) {
    vf4 v = xrow[t + i * 256];  // coalesced
    s += (v.x + v.y) + (v.z + v.w);
  }
#pragma unroll
  for (int off = 32; off > 0; off >>= 1) s += __shfl_down(s, off, 64);
  __shared__ float partial[4];
  if ((t & 63) == 0) partial[t >> 6] = s;
  __syncthreads();
  if (t == 0) {
    float tot = (partial[0] + partial[1]) + (partial[2] + partial[3]);
    means[row] = tot * (1.0f / SE_L);
  }
}

// ---------------------------------------------------------------------------
// Kernel 2 (fused gate+scale): 2048 blocks, each owns 8 contiguous rows of
// ONE batch (64 batches x 32 blocks). Per block: batch means -> LDS, hidden
// layer y[16] computed once (redundant across the batch's 32 blocks -- 16
// MACs/thread, trivial vs 128 KB of streaming), then per row a 16-MAC gate
// dot + sigmoid and the x*g scale with non-temporal stores (nt keeps out
// from thrashing the caches: R1->R3 gave -33 us).
// This removes the tiny 64-block gate dispatch that serialized K1 and K3.
// ---------------------------------------------------------------------------
__global__ __launch_bounds__(256) void se_scale_kernel(
    const float* __restrict__ x, const float* __restrict__ means,
    const float* __restrict__ w1, const float* __restrict__ b1,
    const float* __restrict__ w2, const float* __restrict__ b2,
    float* __restrict__ out) {
  const int t = threadIdx.x;
  const int b = blockIdx.x >> 5;         // batch 0..63
  const int sub = blockIdx.x & 31;       // block-within-batch 0..31
  const int c0 = sub << 3;               // first of 8 rows this block owns

  __shared__ float m_lds[SE_C];
  __shared__ float yp[SE_R][SE_R + 1];
  __shared__ float y_lds[SE_R];

  // batch means -> LDS
  m_lds[t] = means[(b << 8) + t];
  __syncthreads();

  // hidden layer: group g (16 threads) computes y[g]; thread j of the group
  // covers channels j, j+16, ...
  {
    const int g = t >> 4, j = t & 15;
    float part = 0.0f;
    const float* __restrict__ w1g = w1 + (g << 8);
#pragma unroll
    for (int k = 0; k < 16; ++k) {
      const int ch = j + (k << 4);
      part += m_lds[ch] * w1g[ch];
    }
    yp[g][j] = part;
  }
  __syncthreads();
  if (t < SE_R) {
    float acc = b1[t];
#pragma unroll
    for (int k = 0; k < 16; ++k) acc += yp[t][k];
    y_lds[t] = fmaxf(acc, 0.0f);
  }
  __syncthreads();

  // 8 rows: gate (16 MACs, redundant across threads) + stream scale
#pragma unroll 2
  for (int rr = 0; rr < 8; ++rr) {
    const int c = c0 + rr;
    float g = b2[c];
    const float* __restrict__ w2c = w2 + (c << 4);
#pragma unroll
    for (int k = 0; k < SE_R; ++k) g += y_lds[k] * w2c[k];
    g = 1.0f / (1.0f + expf(-g));

    const size_t row = (size_t)(b << 8) + c;
    const vf4* __restrict__ xrow =
        reinterpret_cast<const vf4*>(x + row * SE_L);
    vf4* __restrict__ orow = reinterpret_cast<vf4*>(out + row * SE_L);
#pragma unroll
    for (int i = 0; i < 4; ++i) {
      vf4 v = xrow[t + (i << 8)];
      __builtin_nontemporal_store(v * g, &orow[t + (i << 8)]);
    }
  }
}

extern "C" void kernel_launch(void* const* d_in, const int* in_sizes, int n_in,
                              void* d_out, int out_size, void* d_ws,
                              size_t ws_size, hipStream_t stream) {
  const float* x = (const float*)d_in[0];
  const float* w1 = (const float*)d_in[1];
  const float* b1 = (const float*)d_in[2];
  const float* w2 = (const float*)d_in[3];
  const float* b2 = (const float*)d_in[4];
  float* out = (float*)d_out;

  float* means = (float*)d_ws;  // B*C floats

  se_mean_kernel<<<SE_B * SE_C, 256, 0, stream>>>(x, means);
  se_scale_kernel<<<2048, 256, 0, stream>>>(x, means, w1, b1, w2, b2, out);
}